// Round 1
// baseline (948.229 us; speedup 1.0000x reference)
//
#include <hip/hip_runtime.h>
#include <stdint.h>

// Problem constants
//   B=2, N=2048, C=1024, H=16, D=64, 3C=3072
#define LOGMAX 4.605170185988091f  // log(100)

typedef __attribute__((ext_vector_type(4))) float f32x4;
typedef __attribute__((ext_vector_type(8))) short s16x8;   // 8 bf16 (4 VGPRs)
typedef __attribute__((ext_vector_type(4))) unsigned short u16x4;
typedef unsigned short bh16;

__device__ __forceinline__ bh16 f2bf(float f) {
  union { float f; uint32_t u; } c; c.f = f;
  uint32_t u = c.u;
  u += 0x7fffu + ((u >> 16) & 1u);   // round-to-nearest-even
  return (bh16)(u >> 16);
}

__device__ __forceinline__ void async16(const void* g, void* l) {
  __builtin_amdgcn_global_load_lds((const __attribute__((address_space(1))) void*)g,
                                   (__attribute__((address_space(3))) void*)l, 16, 0, 0);
}

__device__ __forceinline__ f32x4 mfma_bf16(s16x8 a, s16x8 b, f32x4 c) {
  return __builtin_amdgcn_mfma_f32_16x16x32_bf16(a, b, c, 0, 0, 0);
}

// ---------------------------------------------------------------------------
// Kernel 0: fp32 -> bf16 casts for x (4M), qkv_w (3M), proj_w (1M)
// ---------------------------------------------------------------------------
__global__ __launch_bounds__(256) void cast_kernel(
    const float* __restrict__ x, const float* __restrict__ wq, const float* __restrict__ wp,
    bh16* __restrict__ xb, bh16* __restrict__ wqb, bh16* __restrict__ wpb) {
  int i = blockIdx.x * 256 + threadIdx.x;           // chunk of 4 floats
  const float* s; bh16* d; int j;
  if (i < 1048576)      { s = x;  d = xb;  j = i; }
  else if (i < 1835008) { s = wq; d = wqb; j = i - 1048576; }
  else                  { s = wp; d = wpb; j = i - 1835008; }
  f32x4 v = *(const f32x4*)(s + (size_t)j * 4);
  u16x4 o;
  o[0] = f2bf(v[0]); o[1] = f2bf(v[1]); o[2] = f2bf(v[2]); o[3] = f2bf(v[3]);
  *(u16x4*)(d + (size_t)j * 4) = o;
}

// ---------------------------------------------------------------------------
// Kernel 1: QKV GEMM (NT): out3c[m][n'] = sum_k x[m][k]*W[n'][k]
//   M=4096 tokens, N'=3072, K=1024. 128x128 tile, BK=32, 256 thr (4 waves).
//   Epilogue: q,k rows L2-normalized -> Qn/Kn [bh][n][d] bf16 (coalesced via LDS),
//             v transposed -> Vt [bh][d][n] bf16 (coalesced via LDS).
// ---------------------------------------------------------------------------
__global__ __launch_bounds__(256) void qkv_kernel(
    const bh16* __restrict__ xb, const bh16* __restrict__ wqb,
    bh16* __restrict__ Qn, bh16* __restrict__ Kn, bh16* __restrict__ Vt) {
  __shared__ bh16 smem[18432];          // 36864 B: staging 16 KB, epilogue 36 KB (reused)
  bh16* As = smem;                      // [128][32] bf16, row stride 64 B (no pad: global_load_lds)
  bh16* Bs = smem + 4096;               // [128][32]
  const int tid = threadIdx.x;
  const int wave = tid >> 6, lane = tid & 63;
  const int l15 = lane & 15, g = lane >> 4;
  const int m0 = blockIdx.x * 128;      // token rows
  const int n0 = blockIdx.y * 128;      // 3C cols
  const int wm = (wave & 1) * 64, wn = (wave >> 1) * 64;

  f32x4 acc[4][4] = {};

  for (int k0 = 0; k0 < 1024; k0 += 32) {
#pragma unroll
    for (int r = 0; r < 2; ++r) {
      int chunk = r * 256 + tid;                // 512 chunks of 16 B per tile
      int row = chunk >> 2, ko = chunk & 3;
      async16(xb  + (size_t)(m0 + row) * 1024 + k0 + ko * 8, (void*)(As + chunk * 8));
      async16(wqb + (size_t)(n0 + row) * 1024 + k0 + ko * 8, (void*)(Bs + chunk * 8));
    }
    __syncthreads();                            // drains vmcnt (global_load_lds) too
    s16x8 af[4], bfv[4];
#pragma unroll
    for (int i = 0; i < 4; ++i) af[i]  = *(const s16x8*)(As + (wm + i * 16 + l15) * 32 + g * 8);
#pragma unroll
    for (int i = 0; i < 4; ++i) bfv[i] = *(const s16x8*)(Bs + (wn + i * 16 + l15) * 32 + g * 8);
#pragma unroll
    for (int mi = 0; mi < 4; ++mi)
#pragma unroll
      for (int ni = 0; ni < 4; ++ni)
        acc[mi][ni] = mfma_bf16(af[mi], bfv[ni], acc[mi][ni]);
    __syncthreads();
  }

  // epilogue — wave-private LDS repack buffer [64][72] bf16 (stride 144 B, 16B-aligned)
  bh16* ep = smem + wave * 4608;
  const int part = n0 >> 10;                    // 0=q 1=k 2=v (tiles never straddle: 1024%128==0)
  const int h = ((n0 + wn) & 1023) >> 6;
  const int b = m0 >> 11;
  const int tok0 = (m0 & 2047) + wm;
  const int bh = b * 16 + h;

  if (part < 2) {
    // normalize rows over this wave's 64 cols (= exactly one head's D=64)
#pragma unroll
    for (int mi = 0; mi < 4; ++mi) {
#pragma unroll
      for (int r = 0; r < 4; ++r) {
        float ss = 0.f;
#pragma unroll
        for (int ni = 0; ni < 4; ++ni) { float v = acc[mi][ni][r]; ss += v * v; }
        ss += __shfl_xor(ss, 1, 64);
        ss += __shfl_xor(ss, 2, 64);
        ss += __shfl_xor(ss, 4, 64);
        ss += __shfl_xor(ss, 8, 64);
        float rn = rsqrtf(ss);
#pragma unroll
        for (int ni = 0; ni < 4; ++ni)
          ep[(mi * 16 + g * 4 + r) * 72 + ni * 16 + l15] = f2bf(acc[mi][ni][r] * rn);
      }
    }
    // store contiguous 8 KB: Qn/Kn[bh][tok0..tok0+63][0..63]
    bh16* dst = (part == 0 ? Qn : Kn) + ((size_t)bh * 2048 + tok0) * 64;
#pragma unroll
    for (int j = 0; j < 8; ++j) {
      int chunk = j * 64 + lane;
      int row = chunk >> 3, cc = chunk & 7;
      *(s16x8*)(dst + chunk * 8) = *(const s16x8*)(ep + row * 72 + cc * 8);
    }
  } else {
    // v: transpose in LDS -> Vt[bh][d][n]
#pragma unroll
    for (int mi = 0; mi < 4; ++mi)
#pragma unroll
      for (int r = 0; r < 4; ++r)
#pragma unroll
        for (int ni = 0; ni < 4; ++ni)
          ep[(ni * 16 + l15) * 72 + mi * 16 + g * 4 + r] = f2bf(acc[mi][ni][r]);
#pragma unroll
    for (int j = 0; j < 8; ++j) {
      int chunk = j * 64 + lane;
      int drow = chunk >> 3, cc = chunk & 7;
      *(s16x8*)(Vt + ((size_t)bh * 64 + drow) * 2048 + tok0 + cc * 8) =
          *(const s16x8*)(ep + drow * 72 + cc * 8);
    }
  }
}

// ---------------------------------------------------------------------------
// Kernel 2: flash attention. Block = (qtile64, h, b); 4 waves x 16 q-rows.
//   S = scale*Qn·Kn^T + alibi, key-mask -> -inf, online softmax (fp32),
//   P -> LDS (layout transform C->A per m120), O += P·V via Vt.
//   Streams the 537 MB alibi: this is the HBM-bound dispatch.
// ---------------------------------------------------------------------------
__global__ __launch_bounds__(256) void attn_kernel(
    const bh16* __restrict__ Qn, const bh16* __restrict__ Kn, const bh16* __restrict__ Vt,
    const float* __restrict__ alibi, const int* __restrict__ mask,
    const float* __restrict__ lscale, bh16* __restrict__ ao) {
  __shared__ bh16 plds_s[4 * 16 * 72];     // per-wave P buffer [16 q][64 key], stride 72
  const int tid = threadIdx.x;
  const int wave = tid >> 6, lane = tid & 63;
  const int l15 = lane & 15, g = lane >> 4;
  const int qt = blockIdx.x, h = blockIdx.y, b = blockIdx.z;
  const int bh = b * 16 + h;
  const int qbase = qt * 64 + wave * 16;
  bh16* plds = plds_s + wave * (16 * 72);

  const float scale = __expf(fminf(lscale[h], LOGMAX));   // = 10.0 for this input
  const bh16* qp = Qn + ((size_t)bh * 2048 + qbase + l15) * 64 + g * 8;
  const s16x8 aq0 = *(const s16x8*)qp;
  const s16x8 aq1 = *(const s16x8*)(qp + 32);

  f32x4 Oa[4] = {};
  float m_run[4], l_run[4];
#pragma unroll
  for (int r = 0; r < 4; ++r) { m_run[r] = -30.0f; l_run[r] = 0.0f; }  // logits >= -17; keeps m finite

  const float* alp = alibi + ((size_t)(bh * 2048 + qbase + g * 4)) * 2048 + l15;
  const int* mkp = mask + b * 2048 + l15;

  for (int kt = 0; kt < 32; ++kt) {
    const int k0 = kt * 64;
    int mk[4];
#pragma unroll
    for (int nb = 0; nb < 4; ++nb) mk[nb] = mkp[k0 + nb * 16];
    float al[4][4];
#pragma unroll
    for (int r = 0; r < 4; ++r)
#pragma unroll
      for (int nb = 0; nb < 4; ++nb)
        al[r][nb] = alp[(size_t)r * 2048 + k0 + nb * 16];

    f32x4 s[4];
#pragma unroll
    for (int nb = 0; nb < 4; ++nb) {
      const bh16* kp = Kn + ((size_t)bh * 2048 + k0 + nb * 16 + l15) * 64 + g * 8;
      s16x8 bk0 = *(const s16x8*)kp;
      s16x8 bk1 = *(const s16x8*)(kp + 32);
      f32x4 z = {0.f, 0.f, 0.f, 0.f};
      z = mfma_bf16(aq0, bk0, z);
      z = mfma_bf16(aq1, bk1, z);
      s[nb] = z;
    }

#pragma unroll
    for (int r = 0; r < 4; ++r) {
      float rowmax = -3.0e38f;
#pragma unroll
      for (int nb = 0; nb < 4; ++nb) {
        float v = mk[nb] ? -3.0e38f : s[nb][r] * scale + al[r][nb];
        s[nb][r] = v;
        rowmax = fmaxf(rowmax, v);
      }
      rowmax = fmaxf(rowmax, __shfl_xor(rowmax, 1, 64));
      rowmax = fmaxf(rowmax, __shfl_xor(rowmax, 2, 64));
      rowmax = fmaxf(rowmax, __shfl_xor(rowmax, 4, 64));
      rowmax = fmaxf(rowmax, __shfl_xor(rowmax, 8, 64));
      float mnew = fmaxf(m_run[r], rowmax);
      float alpha = __expf(m_run[r] - mnew);
      m_run[r] = mnew;
      float rs = 0.f;
#pragma unroll
      for (int nb = 0; nb < 4; ++nb) {
        float p = __expf(s[nb][r] - mnew);   // masked: exp(-huge)=0
        s[nb][r] = p;
        rs += p;
      }
      rs += __shfl_xor(rs, 1, 64);
      rs += __shfl_xor(rs, 2, 64);
      rs += __shfl_xor(rs, 4, 64);
      rs += __shfl_xor(rs, 8, 64);
      l_run[r] = l_run[r] * alpha + rs;
#pragma unroll
      for (int nd = 0; nd < 4; ++nd) Oa[nd][r] *= alpha;
#pragma unroll
      for (int nb = 0; nb < 4; ++nb)
        plds[(g * 4 + r) * 72 + nb * 16 + l15] = f2bf(s[nb][r]);
    }

    // P (A-layout) from LDS; V B-frags contiguous thanks to Vt layout
    s16x8 ap0 = *(const s16x8*)(plds + l15 * 72 + g * 8);
    s16x8 ap1 = *(const s16x8*)(plds + l15 * 72 + 32 + g * 8);
#pragma unroll
    for (int nd = 0; nd < 4; ++nd) {
      const bh16* vp = Vt + ((size_t)bh * 64 + nd * 16 + l15) * 2048 + k0 + g * 8;
      s16x8 bv0 = *(const s16x8*)vp;
      s16x8 bv1 = *(const s16x8*)(vp + 32);
      Oa[nd] = mfma_bf16(ap0, bv0, Oa[nd]);
      Oa[nd] = mfma_bf16(ap1, bv1, Oa[nd]);
    }
  }

#pragma unroll
  for (int r = 0; r < 4; ++r) {
    float inv = 1.0f / l_run[r];
    size_t rowo = ((size_t)b * 2048 + qbase + g * 4 + r) * 1024 + h * 64 + l15;
#pragma unroll
    for (int nd = 0; nd < 4; ++nd)
      ao[rowo + nd * 16] = f2bf(Oa[nd][r] * inv);
  }
}

// ---------------------------------------------------------------------------
// Kernel 3: proj GEMM (NT) + bias, fp32 out. M=4096, N'=1024, K=1024.
// ---------------------------------------------------------------------------
__global__ __launch_bounds__(256) void proj_kernel(
    const bh16* __restrict__ ab, const bh16* __restrict__ wpb,
    const float* __restrict__ bias, float* __restrict__ out) {
  __shared__ bh16 smem[8192];           // 16 KB staging
  bh16* As = smem;
  bh16* Bs = smem + 4096;
  const int tid = threadIdx.x;
  const int wave = tid >> 6, lane = tid & 63;
  const int l15 = lane & 15, g = lane >> 4;
  const int m0 = blockIdx.x * 128;
  const int n0 = blockIdx.y * 128;
  const int wm = (wave & 1) * 64, wn = (wave >> 1) * 64;

  f32x4 acc[4][4] = {};

  for (int k0 = 0; k0 < 1024; k0 += 32) {
#pragma unroll
    for (int r = 0; r < 2; ++r) {
      int chunk = r * 256 + tid;
      int row = chunk >> 2, ko = chunk & 3;
      async16(ab  + (size_t)(m0 + row) * 1024 + k0 + ko * 8, (void*)(As + chunk * 8));
      async16(wpb + (size_t)(n0 + row) * 1024 + k0 + ko * 8, (void*)(Bs + chunk * 8));
    }
    __syncthreads();
    s16x8 af[4], bfv[4];
#pragma unroll
    for (int i = 0; i < 4; ++i) af[i]  = *(const s16x8*)(As + (wm + i * 16 + l15) * 32 + g * 8);
#pragma unroll
    for (int i = 0; i < 4; ++i) bfv[i] = *(const s16x8*)(Bs + (wn + i * 16 + l15) * 32 + g * 8);
#pragma unroll
    for (int mi = 0; mi < 4; ++mi)
#pragma unroll
      for (int ni = 0; ni < 4; ++ni)
        acc[mi][ni] = mfma_bf16(af[mi], bfv[ni], acc[mi][ni]);
    __syncthreads();
  }

  float bi[4];
#pragma unroll
  for (int ni = 0; ni < 4; ++ni) bi[ni] = bias[n0 + wn + ni * 16 + l15];
#pragma unroll
  for (int mi = 0; mi < 4; ++mi)
#pragma unroll
    for (int r = 0; r < 4; ++r)
#pragma unroll
      for (int ni = 0; ni < 4; ++ni)
        out[(size_t)(m0 + wm + mi * 16 + g * 4 + r) * 1024 + n0 + wn + ni * 16 + l15] =
            acc[mi][ni][r] + bi[ni];
}

// ---------------------------------------------------------------------------
extern "C" void kernel_launch(void* const* d_in, const int* in_sizes, int n_in,
                              void* d_out, int out_size, void* d_ws, size_t ws_size,
                              hipStream_t stream) {
  const float* x     = (const float*)d_in[0];
  const int*   mask  = (const int*)d_in[1];    // padding_mask (bool -> int32 per harness)
  const float* alibi = (const float*)d_in[2];
  const float* qkvw  = (const float*)d_in[3];
  const float* projw = (const float*)d_in[4];
  const float* projb = (const float*)d_in[5];
  const float* lsc   = (const float*)d_in[6];

  char* ws = (char*)d_ws;                       // 48 MB used
  bh16* xb  = (bh16*)(ws);                      //  8 MB  x bf16 [4096][1024]
  bh16* wqb = (bh16*)(ws + 8388608);            //  6 MB  qkv_w bf16 [3072][1024]
  bh16* wpb = (bh16*)(ws + 14680064);           //  2 MB  proj_w bf16 [1024][1024]
  bh16* Qn  = (bh16*)(ws + 16777216);           //  8 MB  normalized Q [bh][n][d]
  bh16* Kn  = (bh16*)(ws + 25165824);           //  8 MB  normalized K [bh][n][d]
  bh16* Vt  = (bh16*)(ws + 33554432);           //  8 MB  V^T [bh][d][n]
  bh16* ao  = (bh16*)(ws + 41943040);           //  8 MB  attn out [b][n][h*64+d]

  cast_kernel<<<8192, 256, 0, stream>>>(x, qkvw, projw, xb, wqb, wpb);
  qkv_kernel<<<dim3(32, 24), 256, 0, stream>>>(xb, wqb, Qn, Kn, Vt);
  attn_kernel<<<dim3(32, 16, 2), 256, 0, stream>>>(Qn, Kn, Vt, alibi, mask, lsc, ao);
  proj_kernel<<<dim3(32, 8), 256, 0, stream>>>(ao, wpb, projb, (float*)d_out);
}

// Round 2
// 822.303 us; speedup vs baseline: 1.1531x; 1.1531x over previous
//
#include <hip/hip_runtime.h>
#include <stdint.h>

// Problem constants
//   B=2, N=2048, C=1024, H=16, D=64, 3C=3072
#define LOGMAX 4.605170185988091f  // log(100)

typedef __attribute__((ext_vector_type(4))) float f32x4;
typedef __attribute__((ext_vector_type(8))) short s16x8;   // 8 bf16 (4 VGPRs)
typedef __attribute__((ext_vector_type(4))) unsigned short u16x4;
typedef unsigned short bh16;

__device__ __forceinline__ bh16 f2bf(float f) {
  union { float f; uint32_t u; } c; c.f = f;
  uint32_t u = c.u;
  u += 0x7fffu + ((u >> 16) & 1u);   // round-to-nearest-even
  return (bh16)(u >> 16);
}

__device__ __forceinline__ void async16(const void* g, void* l) {
  __builtin_amdgcn_global_load_lds((const __attribute__((address_space(1))) void*)g,
                                   (__attribute__((address_space(3))) void*)l, 16, 0, 0);
}

__device__ __forceinline__ f32x4 mfma_bf16(s16x8 a, s16x8 b, f32x4 c) {
  return __builtin_amdgcn_mfma_f32_16x16x32_bf16(a, b, c, 0, 0, 0);
}

// ---------------------------------------------------------------------------
// Kernel 0: fp32 -> bf16 casts for x (4M), qkv_w (3M), proj_w (1M)
// ---------------------------------------------------------------------------
__global__ __launch_bounds__(256) void cast_kernel(
    const float* __restrict__ x, const float* __restrict__ wq, const float* __restrict__ wp,
    bh16* __restrict__ xb, bh16* __restrict__ wqb, bh16* __restrict__ wpb) {
  int i = blockIdx.x * 256 + threadIdx.x;           // chunk of 4 floats
  const float* s; bh16* d; int j;
  if (i < 1048576)      { s = x;  d = xb;  j = i; }
  else if (i < 1835008) { s = wq; d = wqb; j = i - 1048576; }
  else                  { s = wp; d = wpb; j = i - 1835008; }
  f32x4 v = *(const f32x4*)(s + (size_t)j * 4);
  u16x4 o;
  o[0] = f2bf(v[0]); o[1] = f2bf(v[1]); o[2] = f2bf(v[2]); o[3] = f2bf(v[3]);
  *(u16x4*)(d + (size_t)j * 4) = o;
}

// ---------------------------------------------------------------------------
// Kernel 1: QKV GEMM (NT): out3c[m][n'] = sum_k x[m][k]*W[n'][k]
//   M=4096 tokens, N'=3072, K=1024. 128x128 tile, BK=32, 256 thr (4 waves).
//   Epilogue: q,k rows L2-normalized -> Qn/Kn [bh][n][d] bf16,
//             v transposed -> Vt [bh][d][n] bf16.
// ---------------------------------------------------------------------------
__global__ __launch_bounds__(256) void qkv_kernel(
    const bh16* __restrict__ xb, const bh16* __restrict__ wqb,
    bh16* __restrict__ Qn, bh16* __restrict__ Kn, bh16* __restrict__ Vt) {
  __shared__ bh16 smem[18432];          // staging 16 KB; epilogue 36 KB (reused)
  bh16* As = smem;                      // [128][32] bf16
  bh16* Bs = smem + 4096;               // [128][32]
  const int tid = threadIdx.x;
  const int wave = tid >> 6, lane = tid & 63;
  const int l15 = lane & 15, g = lane >> 4;
  const int m0 = blockIdx.x * 128;      // token rows
  const int n0 = blockIdx.y * 128;      // 3C cols
  const int wm = (wave & 1) * 64, wn = (wave >> 1) * 64;

  f32x4 acc[4][4] = {};

  for (int k0 = 0; k0 < 1024; k0 += 32) {
#pragma unroll
    for (int r = 0; r < 2; ++r) {
      int chunk = r * 256 + tid;                // 512 chunks of 16 B per tile
      int row = chunk >> 2, ko = chunk & 3;
      async16(xb  + (size_t)(m0 + row) * 1024 + k0 + ko * 8, (void*)(As + chunk * 8));
      async16(wqb + (size_t)(n0 + row) * 1024 + k0 + ko * 8, (void*)(Bs + chunk * 8));
    }
    __syncthreads();
    s16x8 af[4], bfv[4];
#pragma unroll
    for (int i = 0; i < 4; ++i) af[i]  = *(const s16x8*)(As + (wm + i * 16 + l15) * 32 + g * 8);
#pragma unroll
    for (int i = 0; i < 4; ++i) bfv[i] = *(const s16x8*)(Bs + (wn + i * 16 + l15) * 32 + g * 8);
#pragma unroll
    for (int mi = 0; mi < 4; ++mi)
#pragma unroll
      for (int ni = 0; ni < 4; ++ni)
        acc[mi][ni] = mfma_bf16(af[mi], bfv[ni], acc[mi][ni]);
    __syncthreads();
  }

  // epilogue — wave-private LDS repack buffer [64][72] bf16
  bh16* ep = smem + wave * 4608;
  const int part = n0 >> 10;                    // 0=q 1=k 2=v
  const int h = ((n0 + wn) & 1023) >> 6;
  const int b = m0 >> 11;
  const int tok0 = (m0 & 2047) + wm;
  const int bh = b * 16 + h;

  if (part < 2) {
#pragma unroll
    for (int mi = 0; mi < 4; ++mi) {
#pragma unroll
      for (int r = 0; r < 4; ++r) {
        float ss = 0.f;
#pragma unroll
        for (int ni = 0; ni < 4; ++ni) { float v = acc[mi][ni][r]; ss += v * v; }
        ss += __shfl_xor(ss, 1, 64);
        ss += __shfl_xor(ss, 2, 64);
        ss += __shfl_xor(ss, 4, 64);
        ss += __shfl_xor(ss, 8, 64);
        float rn = rsqrtf(ss);
#pragma unroll
        for (int ni = 0; ni < 4; ++ni)
          ep[(mi * 16 + g * 4 + r) * 72 + ni * 16 + l15] = f2bf(acc[mi][ni][r] * rn);
      }
    }
    bh16* dst = (part == 0 ? Qn : Kn) + ((size_t)bh * 2048 + tok0) * 64;
#pragma unroll
    for (int j = 0; j < 8; ++j) {
      int chunk = j * 64 + lane;
      int row = chunk >> 3, cc = chunk & 7;
      *(s16x8*)(dst + chunk * 8) = *(const s16x8*)(ep + row * 72 + cc * 8);
    }
  } else {
#pragma unroll
    for (int mi = 0; mi < 4; ++mi)
#pragma unroll
      for (int r = 0; r < 4; ++r)
#pragma unroll
        for (int ni = 0; ni < 4; ++ni)
          ep[(ni * 16 + l15) * 72 + mi * 16 + g * 4 + r] = f2bf(acc[mi][ni][r]);
#pragma unroll
    for (int j = 0; j < 8; ++j) {
      int chunk = j * 64 + lane;
      int drow = chunk >> 3, cc = chunk & 7;
      *(s16x8*)(Vt + ((size_t)bh * 64 + drow) * 2048 + tok0 + cc * 8) =
          *(const s16x8*)(ep + drow * 72 + cc * 8);
    }
  }
}

// ---------------------------------------------------------------------------
// Kernel 2: flash attention, S^T formulation.
//   Block = (qtile64, h, b); 4 waves x 16 queries each (q = lane&15).
//   S^T = K·Q^T: C-layout row = key (g*4+r contiguous!), col = query (l15)
//     -> alibi loads are float4, mask int4, softmax state scalar per lane.
//   K/V tiles staged in LDS (shared by 4 waves) via global_load_lds with
//   16B-chunk XOR swizzle (2-way conflict = free).
// ---------------------------------------------------------------------------
__global__ __launch_bounds__(256) void attn_kernel(
    const bh16* __restrict__ Qn, const bh16* __restrict__ Kn, const bh16* __restrict__ Vt,
    const float* __restrict__ alibi, const int* __restrict__ mask,
    const float* __restrict__ lscale, bh16* __restrict__ ao) {
  __shared__ bh16 klds[4096];            // [64 key][64 d], 16B chunks swizzled
  __shared__ bh16 vlds[4096];            // [64 d][64 key], swizzled
  __shared__ bh16 plds_s[4 * 16 * 72];   // per-wave P^T->A transform [16 q][64 k]
  const int tid = threadIdx.x;
  const int wave = tid >> 6, lane = tid & 63;
  const int l15 = lane & 15, g = lane >> 4;
  const int qt = blockIdx.x, h = blockIdx.y, b = blockIdx.z;
  const int bh = b * 16 + h;
  const int qw = qt * 64 + wave * 16;
  bh16* plds = plds_s + wave * (16 * 72);

  const float scale = __expf(fminf(lscale[h], LOGMAX));
  // Q fragment = B operand (n = q = l15), reused all iterations
  const bh16* qp = Qn + ((size_t)bh * 2048 + qw + l15) * 64 + g * 8;
  const s16x8 bq0 = *(const s16x8*)qp;
  const s16x8 bq1 = *(const s16x8*)(qp + 32);

  const bh16* Kb = Kn + (size_t)bh * 2048 * 64;
  const bh16* Vb = Vt + (size_t)bh * 64 * 2048;
  const float* alibase = alibi + ((size_t)bh * 2048 + qw + l15) * 2048;
  const int* mbase = mask + b * 2048;

  // staging slots: 512 chunks of 16B per tile; chunk c -> row c>>3, slot c&7,
  // holds global 16B-chunk u = (c&7) ^ (row&7)
  const int c0 = wave * 64 + lane;
  const int c1 = 256 + wave * 64 + lane;
  const int r0 = c0 >> 3, u0 = (c0 & 7) ^ (r0 & 7);
  const int r1 = c1 >> 3, u1 = (c1 & 7) ^ (r1 & 7);

  f32x4 Oa[4] = {};
  float m_run = -30.0f, l_run = 0.0f;

  // prefetch alibi(+mask folded) for kt=0
  f32x4 al[4];
#pragma unroll
  for (int nb = 0; nb < 4; ++nb) {
    f32x4 a = *(const f32x4*)(alibase + nb * 16 + g * 4);
    int4 m4 = *(const int4*)(mbase + nb * 16 + g * 4);
    al[nb][0] = m4.x ? -3.0e38f : a[0];
    al[nb][1] = m4.y ? -3.0e38f : a[1];
    al[nb][2] = m4.z ? -3.0e38f : a[2];
    al[nb][3] = m4.w ? -3.0e38f : a[3];
  }

  for (int kt = 0; kt < 32; ++kt) {
    const int k0 = kt * 64;
    // stage K tile [key][d] and V tile [d][key] (swizzled)
    async16(Kb + (size_t)(k0 + r0) * 64 + u0 * 8, (void*)(klds + c0 * 8));
    async16(Kb + (size_t)(k0 + r1) * 64 + u1 * 8, (void*)(klds + c1 * 8));
    async16(Vb + (size_t)r0 * 2048 + k0 + u0 * 8, (void*)(vlds + c0 * 8));
    async16(Vb + (size_t)r1 * 2048 + k0 + u1 * 8, (void*)(vlds + c1 * 8));
    __syncthreads();

    // prefetch next tile's alibi/mask (full-iteration latency cover)
    f32x4 aln[4];
    if (kt < 31) {
      const int k1 = k0 + 64;
#pragma unroll
      for (int nb = 0; nb < 4; ++nb) {
        f32x4 a = *(const f32x4*)(alibase + k1 + nb * 16 + g * 4);
        int4 m4 = *(const int4*)(mbase + k1 + nb * 16 + g * 4);
        aln[nb][0] = m4.x ? -3.0e38f : a[0];
        aln[nb][1] = m4.y ? -3.0e38f : a[1];
        aln[nb][2] = m4.z ? -3.0e38f : a[2];
        aln[nb][3] = m4.w ? -3.0e38f : a[3];
      }
    }

    // S^T = K·Q^T : A = K rows (m=k), B = Q rows (n=q)
    f32x4 s[4];
#pragma unroll
    for (int nb = 0; nb < 4; ++nb) {
      const int kr = nb * 16 + l15;
      s16x8 ak0 = *(const s16x8*)(klds + kr * 64 + ((g ^ (kr & 7)) * 8));
      s16x8 ak1 = *(const s16x8*)(klds + kr * 64 + (((g + 4) ^ (kr & 7)) * 8));
      f32x4 z = {0.f, 0.f, 0.f, 0.f};
      z = mfma_bf16(ak0, bq0, z);
      z = mfma_bf16(ak1, bq1, z);
      s[nb] = z;
    }

    // online softmax over keys; per-lane q = l15, key reduction = xor16/32
    float lm = -3.0e38f;
#pragma unroll
    for (int nb = 0; nb < 4; ++nb)
#pragma unroll
      for (int r = 0; r < 4; ++r) {
        float v = s[nb][r] * scale + al[nb][r];   // masked: -3e38 addend
        s[nb][r] = v;
        lm = fmaxf(lm, v);
      }
    lm = fmaxf(lm, __shfl_xor(lm, 16, 64));
    lm = fmaxf(lm, __shfl_xor(lm, 32, 64));
    float mnew = fmaxf(m_run, lm);
    float alpha = __expf(m_run - mnew);
    m_run = mnew;
    float rs = 0.f;
#pragma unroll
    for (int nb = 0; nb < 4; ++nb)
#pragma unroll
      for (int r = 0; r < 4; ++r) {
        float p = __expf(s[nb][r] - mnew);
        s[nb][r] = p;
        rs += p;
      }
    rs += __shfl_xor(rs, 16, 64);
    rs += __shfl_xor(rs, 32, 64);
    l_run = l_run * alpha + rs;
#pragma unroll
    for (int nd = 0; nd < 4; ++nd)
#pragma unroll
      for (int r = 0; r < 4; ++r) Oa[nd][r] *= alpha;

    // P^T -> plds [q][k], 4x 8B vector stores per lane (r contiguous in k)
#pragma unroll
    for (int nb = 0; nb < 4; ++nb) {
      u16x4 pk;
      pk[0] = f2bf(s[nb][0]); pk[1] = f2bf(s[nb][1]);
      pk[2] = f2bf(s[nb][2]); pk[3] = f2bf(s[nb][3]);
      *(u16x4*)(plds + l15 * 72 + nb * 16 + g * 4) = pk;
    }

    // O^T tile: A = V rows (m=d) from vlds, B = P rows (n=q) from plds
    s16x8 bp0 = *(const s16x8*)(plds + l15 * 72 + g * 8);
    s16x8 bp1 = *(const s16x8*)(plds + l15 * 72 + 32 + g * 8);
#pragma unroll
    for (int nd = 0; nd < 4; ++nd) {
      const int dr = nd * 16 + l15;
      s16x8 av0 = *(const s16x8*)(vlds + dr * 64 + ((g ^ (dr & 7)) * 8));
      s16x8 av1 = *(const s16x8*)(vlds + dr * 64 + (((g + 4) ^ (dr & 7)) * 8));
      Oa[nd] = mfma_bf16(av0, bp0, Oa[nd]);
      Oa[nd] = mfma_bf16(av1, bp1, Oa[nd]);
    }
    __syncthreads();   // klds/vlds consumed; safe to restage
    if (kt < 31) {
#pragma unroll
      for (int nb = 0; nb < 4; ++nb) al[nb] = aln[nb];
    }
  }

  // epilogue: O[q=l15][d = nd*16 + g*4 + r] -> vectorized u16x4 stores
  const float inv = 1.0f / l_run;
  const size_t rowo = ((size_t)b * 2048 + qw + l15) * 1024 + h * 64;
#pragma unroll
  for (int nd = 0; nd < 4; ++nd) {
    u16x4 o;
    o[0] = f2bf(Oa[nd][0] * inv); o[1] = f2bf(Oa[nd][1] * inv);
    o[2] = f2bf(Oa[nd][2] * inv); o[3] = f2bf(Oa[nd][3] * inv);
    *(u16x4*)(ao + rowo + nd * 16 + g * 4) = o;
  }
}

// ---------------------------------------------------------------------------
// Kernel 3: proj GEMM (NT) + bias, fp32 out. M=4096, N'=1024, K=1024.
// ---------------------------------------------------------------------------
__global__ __launch_bounds__(256) void proj_kernel(
    const bh16* __restrict__ ab, const bh16* __restrict__ wpb,
    const float* __restrict__ bias, float* __restrict__ out) {
  __shared__ bh16 smem[8192];           // 16 KB staging
  bh16* As = smem;
  bh16* Bs = smem + 4096;
  const int tid = threadIdx.x;
  const int wave = tid >> 6, lane = tid & 63;
  const int l15 = lane & 15, g = lane >> 4;
  const int m0 = blockIdx.x * 128;
  const int n0 = blockIdx.y * 128;
  const int wm = (wave & 1) * 64, wn = (wave >> 1) * 64;

  f32x4 acc[4][4] = {};

  for (int k0 = 0; k0 < 1024; k0 += 32) {
#pragma unroll
    for (int r = 0; r < 2; ++r) {
      int chunk = r * 256 + tid;
      int row = chunk >> 2, ko = chunk & 3;
      async16(ab  + (size_t)(m0 + row) * 1024 + k0 + ko * 8, (void*)(As + chunk * 8));
      async16(wpb + (size_t)(n0 + row) * 1024 + k0 + ko * 8, (void*)(Bs + chunk * 8));
    }
    __syncthreads();
    s16x8 af[4], bfv[4];
#pragma unroll
    for (int i = 0; i < 4; ++i) af[i]  = *(const s16x8*)(As + (wm + i * 16 + l15) * 32 + g * 8);
#pragma unroll
    for (int i = 0; i < 4; ++i) bfv[i] = *(const s16x8*)(Bs + (wn + i * 16 + l15) * 32 + g * 8);
#pragma unroll
    for (int mi = 0; mi < 4; ++mi)
#pragma unroll
      for (int ni = 0; ni < 4; ++ni)
        acc[mi][ni] = mfma_bf16(af[mi], bfv[ni], acc[mi][ni]);
    __syncthreads();
  }

  float bi[4];
#pragma unroll
  for (int ni = 0; ni < 4; ++ni) bi[ni] = bias[n0 + wn + ni * 16 + l15];
#pragma unroll
  for (int mi = 0; mi < 4; ++mi)
#pragma unroll
    for (int r = 0; r < 4; ++r)
#pragma unroll
      for (int ni = 0; ni < 4; ++ni)
        out[(size_t)(m0 + wm + mi * 16 + g * 4 + r) * 1024 + n0 + wn + ni * 16 + l15] =
            acc[mi][ni][r] + bi[ni];
}

// ---------------------------------------------------------------------------
extern "C" void kernel_launch(void* const* d_in, const int* in_sizes, int n_in,
                              void* d_out, int out_size, void* d_ws, size_t ws_size,
                              hipStream_t stream) {
  const float* x     = (const float*)d_in[0];
  const int*   mask  = (const int*)d_in[1];    // padding_mask (bool -> int32)
  const float* alibi = (const float*)d_in[2];
  const float* qkvw  = (const float*)d_in[3];
  const float* projw = (const float*)d_in[4];
  const float* projb = (const float*)d_in[5];
  const float* lsc   = (const float*)d_in[6];

  char* ws = (char*)d_ws;                       // 48 MB used
  bh16* xb  = (bh16*)(ws);                      //  8 MB  x bf16 [4096][1024]
  bh16* wqb = (bh16*)(ws + 8388608);            //  6 MB  qkv_w bf16 [3072][1024]
  bh16* wpb = (bh16*)(ws + 14680064);           //  2 MB  proj_w bf16 [1024][1024]
  bh16* Qn  = (bh16*)(ws + 16777216);           //  8 MB  normalized Q [bh][n][d]
  bh16* Kn  = (bh16*)(ws + 25165824);           //  8 MB  normalized K [bh][n][d]
  bh16* Vt  = (bh16*)(ws + 33554432);           //  8 MB  V^T [bh][d][n]
  bh16* ao  = (bh16*)(ws + 41943040);           //  8 MB  attn out [b][n][h*64+d]

  cast_kernel<<<8192, 256, 0, stream>>>(x, qkvw, projw, xb, wqb, wpb);
  qkv_kernel<<<dim3(32, 24), 256, 0, stream>>>(xb, wqb, Qn, Kn, Vt);
  attn_kernel<<<dim3(32, 16, 2), 256, 0, stream>>>(Qn, Kn, Vt, alibi, mask, lsc, ao);
  proj_kernel<<<dim3(32, 8), 256, 0, stream>>>(ao, wpb, projb, (float*)d_out);
}